// Round 4
// baseline (124.640 us; speedup 1.0000x reference)
//
#include <hip/hip_runtime.h>

#define HW    256
#define HW2   (HW*HW)
#define KTAPS 25
#define TW    16          // tile width  (outputs) — 2 px/thread keeps wt[] at 50 VGPRs
#define TH    8           // tile height (outputs)
#define LW    20          // LDS row length (TW + 4); 80 B rows
#define LH    12          // TH + 4
#define NEL   (LW*LH)     // 240
#define NSTG  4           // ceil(240/64); stage covers 256 slots (overrun benign, buffer sized for it)
#define BUFSZ (NSTG*64)   // 256 floats per ring buffer
#define NRING 4
#define DEPTH 2           // channels in flight. DO NOT RAISE TO 3 (round-3 post-mortem):
                          // with a one-iteration read->overwrite gap, the compiler may sink
                          // the consuming FMAs+store below the overwriting stage(), and the
                          // async gload_lds LDS-write can overtake a still-queued ds_read.
                          // DEPTH=2 is provably safe: store(cc-2) (pinned by the asm memory
                          // clobbers) data-depends on ds_read(cc-2), so slot reads complete
                          // before the overwriting DMA is issued.
#define CPB   8           // channels per block (channel-split = 4)
#define C     32

// Issue the 4 async global->LDS loads for one channel tile.
// Global source is per-lane (clamped edge-replicate folded into soff);
// LDS dest is wave-uniform base + lane*4 (hardware layout), matching idx = k*64 + lane.
__device__ __forceinline__ void stage(const float* __restrict__ src, float* dst,
                                      const int* __restrict__ soff) {
#pragma unroll
    for (int k = 0; k < NSTG; ++k)
        __builtin_amdgcn_global_load_lds(
            (const __attribute__((address_space(1))) unsigned int*)(src + soff[k]),
            (__attribute__((address_space(3))) unsigned int*)(dst + k * 64),
            4, 0, 0);
}

// launch_bounds(64,5): unified cap ~102 regs. Live set ≈ 90 (50 wt + 4 soff + ~35
// addressing/accum/staging) -> pure-VGPR, no AGPR parking of wt[] (the 4px version's
// 25 weight loads serialized through an AGPR round-trip at ~470cy each). If
// WRITE_SIZE > 40 MB this cap spilled: drop to (64,4), not (64,3).
__global__ __launch_bounds__(64, 5) void ddown_kernel(
    const float* __restrict__ x,
    const float* __restrict__ kern,
    float* __restrict__ out)
{
    __shared__ __align__(16) float xt[NRING][BUFSZ];   // 4 * 1024 B = 4096 B

    const int lane = threadIdx.x;      // one wave per block: no __syncthreads anywhere
    const int txq  = lane & 7;         // 8 thread-columns of 2 outputs
    const int ty   = lane >> 3;        // 8 rows
    const int w0   = blockIdx.x * TW;
    const int h0   = blockIdx.y * TH;
    const int b    = blockIdx.z >> 2;
    const int c0   = (blockIdx.z & 3) * CPB;

    const int h = h0 + ty;
    const int w = w0 + txq * 2;

    const float* xb = x + (size_t)(b * C + c0) * HW2;

    // Per-lane clamped source offsets, hoisted out of the channel loop.
    // k=3 lanes 48..63 map to idx 240..255 -> i=12, clamped-valid pad slots.
    int soff[NSTG];
#pragma unroll
    for (int k = 0; k < NSTG; ++k) {
        int idx = lane + k * 64;
        int i   = idx / LW;
        int j   = idx - i * LW;
        int hh  = min(max(h0 + i - 2, 0), HW - 1);
        int ww  = min(max(w0 + j - 2, 0), HW - 1);
        soff[k] = hh * HW + ww;
    }

    // Prologue: channels 0 and 1 in flight before the softmax phase even starts.
    stage(xb,       xt[0], soff);
    stage(xb + HW2, xt[1], soff);

    // ---- softmax weights for this thread's 2 pixels (unnormalized; fold 1/S later) ----
    // 25 float2 loads into 50 distinct VGPRs: independent, issue back-to-back.
    const float* kb = kern + (size_t)b * KTAPS * HW2 + h * HW + w;
    float2 wt[KTAPS];
    float sx = 0.f, sy = 0.f;
#pragma unroll
    for (int j = 0; j < KTAPS; ++j) {
        float2 v = *(const float2*)(kb + (size_t)j * HW2);
        v.x = __expf(v.x); v.y = __expf(v.y);
        sx += v.x; sy += v.y;
        wt[j] = v;
    }
    const float ix = 1.f / sx, iy = 1.f / sy;

    float* ob = out + (size_t)(b * C + c0) * HW2 + h * HW + w;

#pragma unroll
    for (int cc = 0; cc < CPB; ++cc) {
        // Keep the pipeline 2 deep: issue channel cc+2 BEFORE waiting on cc.
        if (cc + DEPTH < CPB) stage(xb + (size_t)(cc + DEPTH) * HW2, xt[(cc + DEPTH) % NRING], soff);

        // Counted waits (never vmcnt(0) in steady state). FIFO accounting, loads only
        // (stores ticking vmcnt only makes these stricter): newer-than-S_cc = 4*DEPTH = 8.
        if (cc < 6)       asm volatile("s_waitcnt vmcnt(8)" ::: "memory");
        else if (cc == 6) asm volatile("s_waitcnt vmcnt(4)" ::: "memory");
        else              asm volatile("s_waitcnt vmcnt(0)" ::: "memory");

        const float* xc = xt[cc % NRING];
        float ax = 0.f, ay = 0.f;
#pragma unroll
        for (int di = 0; di < 5; ++di) {
            const float* row = &xc[(ty + di) * LW + txq * 2];
            float2 pa = *(const float2*)(row);      // ds_read_b64 x3 (8B-aligned)
            float2 pb = *(const float2*)(row + 2);
            float2 pc = *(const float2*)(row + 4);
            float w6[6] = {pa.x, pa.y, pb.x, pb.y, pc.x, pc.y};
#pragma unroll
            for (int dj = 0; dj < 5; ++dj) {
                float2 wv = wt[di * 5 + dj];
                ax += wv.x * w6[dj + 0];
                ay += wv.y * w6[dj + 1];
            }
        }
        float2 res = { ax * ix, ay * iy };
        *(float2*)(ob + (size_t)cc * HW2) = res;
    }
}

extern "C" void kernel_launch(void* const* d_in, const int* in_sizes, int n_in,
                              void* d_out, int out_size, void* d_ws, size_t ws_size,
                              hipStream_t stream) {
    const float* x    = (const float*)d_in[0];
    const float* kern = (const float*)d_in[1];
    float* out        = (float*)d_out;

    dim3 grid(HW / TW, HW / TH, 4 * 4);   // (16, 32, 16) = 8192 single-wave blocks
    ddown_kernel<<<grid, 64, 0, stream>>>(x, kern, out);
}

// Round 5
// 114.435 us; speedup vs baseline: 1.0892x; 1.0892x over previous
//
#include <hip/hip_runtime.h>

#define HW    256
#define HW2   (HW*HW)
#define KTAPS 25
#define TW    32          // tile width (outputs): 32 px rows = 128 B per wave-row segment
                          // for kern loads AND output stores (full cache lines — round-4's
                          // 16-px tile caused RFO on half-line stores: FETCH 58->100 MB)
#define TH    4           // tile height (outputs); 64 lanes = 16 cols x 4 rows, 2 px/thread
#define LW    36          // LDS row length (TW + 4); 144 B rows
#define LH    8           // TH + 4
#define NEL   (LW*LH)     // 288
#define NSTG  5           // ceil(288/64); stage covers 320 slots (overrun benign, buffer sized)
#define BUFSZ (NSTG*64)   // 320 floats per ring buffer
#define NRING 4
#define DEPTH 2           // channels in flight. DO NOT RAISE TO 3 (round-3 post-mortem):
                          // one-iteration read->overwrite gap lets the async gload_lds
                          // LDS-write overtake a still-queued ds_read. DEPTH=2 is provably
                          // safe: store(cc-2) (pinned by asm memory clobbers) data-depends
                          // on ds_read(cc-2), so slot reads complete before the
                          // overwriting DMA is issued.
#define CPB   8           // channels per block (channel-split = 4)
#define C     32

// Issue the 5 async global->LDS loads for one channel tile.
// Global source is per-lane (clamped edge-replicate folded into soff);
// LDS dest is wave-uniform base + lane*4 (hardware layout), matching idx = k*64 + lane.
__device__ __forceinline__ void stage(const float* __restrict__ src, float* dst,
                                      const int* __restrict__ soff) {
#pragma unroll
    for (int k = 0; k < NSTG; ++k)
        __builtin_amdgcn_global_load_lds(
            (const __attribute__((address_space(1))) unsigned int*)(src + soff[k]),
            (__attribute__((address_space(3))) unsigned int*)(dst + k * 64),
            4, 0, 0);
}

// launch_bounds(64,5): unified cap ~102 regs. Live set ≈ 90 (50 wt + 5 soff + ~35
// addressing/accum). Round 4 confirmed: no spill at this cap (WRITE stayed at the
// pure-output 32.8 MB). If WRITE_SIZE ever exceeds ~40 MB, drop to (64,4).
__global__ __launch_bounds__(64, 5) void ddown_kernel(
    const float* __restrict__ x,
    const float* __restrict__ kern,
    float* __restrict__ out)
{
    __shared__ __align__(16) float xt[NRING][BUFSZ];   // 4 * 1280 B = 5120 B

    const int lane = threadIdx.x;      // one wave per block: no __syncthreads anywhere
    const int txq  = lane & 15;        // 16 thread-columns of 2 outputs -> 32 px = 128 B rows
    const int ty   = lane >> 4;        // 4 rows
    const int w0   = blockIdx.x * TW;
    const int h0   = blockIdx.y * TH;
    const int b    = blockIdx.z >> 2;
    const int c0   = (blockIdx.z & 3) * CPB;

    const int h = h0 + ty;
    const int w = w0 + txq * 2;

    const float* xb = x + (size_t)(b * C + c0) * HW2;

    // Per-lane clamped source offsets, hoisted out of the channel loop.
    // k=4 lanes 32..63 map to idx 288..319 -> i=8 (one past halo bottom), clamped-valid
    // reads into the buffer's pad slots. No masking needed.
    int soff[NSTG];
#pragma unroll
    for (int k = 0; k < NSTG; ++k) {
        int idx = lane + k * 64;
        int i   = idx / LW;
        int j   = idx - i * LW;
        int hh  = min(max(h0 + i - 2, 0), HW - 1);
        int ww  = min(max(w0 + j - 2, 0), HW - 1);
        soff[k] = hh * HW + ww;
    }

    // Prologue: channels 0 and 1 in flight before the softmax phase even starts.
    stage(xb,       xt[0], soff);
    stage(xb + HW2, xt[1], soff);

    // ---- softmax weights for this thread's 2 pixels (unnormalized; fold 1/S later) ----
    // 25 float2 loads into 50 distinct VGPRs: independent, issue back-to-back.
    // Each wave-row reads 32 px = 128 B contiguous: full cache lines.
    const float* kb = kern + (size_t)b * KTAPS * HW2 + h * HW + w;
    float2 wt[KTAPS];
    float sx = 0.f, sy = 0.f;
#pragma unroll
    for (int j = 0; j < KTAPS; ++j) {
        float2 v = *(const float2*)(kb + (size_t)j * HW2);
        v.x = __expf(v.x); v.y = __expf(v.y);
        sx += v.x; sy += v.y;
        wt[j] = v;
    }
    const float ix = 1.f / sx, iy = 1.f / sy;

    float* ob = out + (size_t)(b * C + c0) * HW2 + h * HW + w;

#pragma unroll
    for (int cc = 0; cc < CPB; ++cc) {
        // Keep the pipeline 2 deep: issue channel cc+2 BEFORE waiting on cc.
        if (cc + DEPTH < CPB) stage(xb + (size_t)(cc + DEPTH) * HW2, xt[(cc + DEPTH) % NRING], soff);

        // Counted waits (never vmcnt(0) in steady state). FIFO accounting, loads only:
        // stages newer than S_cc = NSTG * DEPTH = 10.
        if (cc < 6)       asm volatile("s_waitcnt vmcnt(10)" ::: "memory");
        else if (cc == 6) asm volatile("s_waitcnt vmcnt(5)"  ::: "memory");
        else              asm volatile("s_waitcnt vmcnt(0)"  ::: "memory");

        const float* xc = xt[cc % NRING];
        float ax = 0.f, ay = 0.f;
#pragma unroll
        for (int di = 0; di < 5; ++di) {
            const float* row = &xc[(ty + di) * LW + txq * 2];
            float2 pa = *(const float2*)(row);      // ds_read_b64: 64 lanes x 8 B = exact
            float2 pb = *(const float2*)(row + 2);  //   2-lane/bank aliasing (free, m136)
            float2 pc = *(const float2*)(row + 4);
            float w6[6] = {pa.x, pa.y, pb.x, pb.y, pc.x, pc.y};
#pragma unroll
            for (int dj = 0; dj < 5; ++dj) {
                float2 wv = wt[di * 5 + dj];
                ax += wv.x * w6[dj + 0];
                ay += wv.y * w6[dj + 1];
            }
        }
        float2 res = { ax * ix, ay * iy };
        *(float2*)(ob + (size_t)cc * HW2) = res;   // wave-row = 128 B full-line stores
    }
}

extern "C" void kernel_launch(void* const* d_in, const int* in_sizes, int n_in,
                              void* d_out, int out_size, void* d_ws, size_t ws_size,
                              hipStream_t stream) {
    const float* x    = (const float*)d_in[0];
    const float* kern = (const float*)d_in[1];
    float* out        = (float*)d_out;

    dim3 grid(HW / TW, HW / TH, 4 * 4);   // (8, 64, 16) = 8192 single-wave blocks
    ddown_kernel<<<grid, 64, 0, stream>>>(x, kern, out);
}